// Round 2
// baseline (605.607 us; speedup 1.0000x reference)
//
#include <hip/hip_runtime.h>
#include <hip/hip_fp16.h>
#include <math.h>

// B=16, N=16384, C_IN=C_OUT=128, K=9
#define B_ 16
#define N_ 16384
#define C_ 128
#define K_ 9
#define FCONV 1152           // K_*C_
#define G_ 2                 // nodes per block
#define FPAD 1160            // flat row stride in halfs: 16B-aligned; 145*16B/row -> read-side conflict-free
#define LDS_BYTES (G_ * B_ * FPAD * 2)   // 74240 B dynamic LDS -> 2 blocks/CU

typedef _Float16 half8 __attribute__((ext_vector_type(8)));
typedef _Float16 half2v __attribute__((ext_vector_type(2)));
typedef float floatx4 __attribute__((ext_vector_type(4)));

__device__ __forceinline__ float elu_f(float v) {
    return v > 0.f ? v : (__expf(v) - 1.f);
}

// ---------------- prep: x -> f16, W -> MFMA b-fragment-major f16 ----------------
//  conv frag: ((ot*36 + kc)*64 + lane)*8 + j = Wc[ot*16 + (lane&15)][kc*32 + (lane>>4)*8 + j]
//  skip frag: ((ot*4  + kc)*64 + lane)*8 + j = Ws[ot*16 + (lane&15)][kc*32 + (lane>>4)*8 + j]
__global__ __launch_bounds__(1024) void prep(
    const float* __restrict__ x, const float* __restrict__ Wc, const float* __restrict__ Ws,
    _Float16* __restrict__ x16, _Float16* __restrict__ WcF, _Float16* __restrict__ WsF)
{
    const int t = blockIdx.x * 1024 + threadIdx.x;
    const int NX8 = B_ * N_ * C_ / 8;   // 4,194,304 half8 groups
    if (t < NX8) {
        const float4 a = ((const float4*)x)[(size_t)t * 2];
        const float4 b = ((const float4*)x)[(size_t)t * 2 + 1];
        half8 h = {(_Float16)a.x, (_Float16)a.y, (_Float16)a.z, (_Float16)a.w,
                   (_Float16)b.x, (_Float16)b.y, (_Float16)b.z, (_Float16)b.w};
        *(half8*)(x16 + (size_t)t * 8) = h;
    } else {
        const int i = t - NX8;
        if (i < 8 * 36 * 64 * 8) {
            const int j = i & 7, lane = (i >> 3) & 63;
            const int rest = i >> 9;               // ot*36 + kc
            const int kc = rest % 36, ot = rest / 36;
            WcF[i] = (_Float16)Wc[(size_t)(ot * 16 + (lane & 15)) * FCONV + kc * 32 + (lane >> 4) * 8 + j];
        } else {
            const int i2 = i - 8 * 36 * 64 * 8;
            if (i2 < 8 * 4 * 64 * 8) {
                const int j = i2 & 7, lane = (i2 >> 3) & 63;
                const int rest = i2 >> 9;          // ot*4 + kc
                const int kc = rest & 3, ot = rest >> 2;
                WsF[i2] = (_Float16)Ws[(size_t)(ot * 16 + (lane & 15)) * C_ + kc * 32 + (lane >> 4) * 8 + j];
            }
        }
    }
}

// legacy weight-only prep (fallback when ws fits weights but not x16)
__global__ void build_wfrag(const float* __restrict__ Wc, const float* __restrict__ Ws,
                            _Float16* __restrict__ WcF, _Float16* __restrict__ WsF) {
    const int i = blockIdx.x * 256 + threadIdx.x;
    if (i < 8 * 36 * 64 * 8) {
        const int j = i & 7, lane = (i >> 3) & 63;
        const int rest = i >> 9;
        const int kc = rest % 36, ot = rest / 36;
        WcF[i] = (_Float16)Wc[(size_t)(ot * 16 + (lane & 15)) * FCONV + kc * 32 + (lane >> 4) * 8 + j];
    }
    if (i < 8 * 4 * 64 * 8) {
        const int j = i & 7, lane = (i >> 3) & 63;
        const int rest = i >> 9;
        const int kc = rest & 3, ot = rest >> 2;
        WsF[i] = (_Float16)Ws[(size_t)(ot * 16 + (lane & 15)) * C_ + kc * 32 + (lane >> 4) * 8 + j];
    }
}

template <bool XF16, bool WF16>
__global__ __launch_bounds__(1024, 8) void paiconv_mfma(
    const float*    __restrict__ x,      // (B,N,C) f32
    const _Float16* __restrict__ x16,    // (B,N,C) f16 (XF16 only)
    const int*      __restrict__ idx,    // (N,K)
    const float*    __restrict__ P,      // (N,K,K)
    const void*     __restrict__ WcP,    // WF16: fragment-major f16; else f32 row-major (C_OUT, K*C)
    const float*    __restrict__ bc,
    const void*     __restrict__ WsP,
    const float*    __restrict__ bs,
    float*          __restrict__ out)    // (B,N,C_OUT)
{
    extern __shared__ _Float16 flat_s[];     // [G][16][FPAD] f16

    const int tid = threadIdx.x;
    const int n0  = blockIdx.x * G_;

    // ---------------- phase 1: gather + P-mix + ELU -> flat_s (f16) ----------------
    // thread = (m = tid>>6 batch == wave id, cp = tid&63 channel-pair).
    // Wave gather load = one full 256B neighbour row (f16). LDS store = packed b32, conflict-free.
    // idx/P are wave-uniform -> s_load (SGPRs), no LDS staging.
    {
        const int cp = tid & 63;
        const int m  = tid >> 6;
        #pragma unroll
        for (int g = 0; g < G_; ++g) {
            const int n = n0 + g;
            int id[K_];
            #pragma unroll
            for (int j = 0; j < K_; ++j) id[j] = idx[(size_t)n * K_ + j];   // uniform

            float vx[K_], vy[K_];
            #pragma unroll
            for (int j = 0; j < K_; ++j) {
                const bool ok = (unsigned)id[j] < (unsigned)N_;
                if (XF16) {
                    const _Float16* q = x16 + ((size_t)m * N_ + id[j]) * C_ + 2 * cp;
                    half2v h = ok ? *(const half2v*)q : (half2v){(_Float16)0.f, (_Float16)0.f};
                    vx[j] = (float)h[0]; vy[j] = (float)h[1];
                } else {
                    const float* q = x + ((size_t)m * N_ + id[j]) * C_ + 2 * cp;
                    float2 h = ok ? *(const float2*)q : (float2){0.f, 0.f};
                    vx[j] = h.x; vy[j] = h.y;
                }
            }

            const float* Pn = P + (size_t)n * 81;
            _Float16* fg = &flat_s[g * (B_ * FPAD) + m * FPAD + 2 * cp];
            #pragma unroll
            for (int k = 0; k < K_; ++k) {
                float s0 = 0.f, s1 = 0.f;
                #pragma unroll
                for (int j = 0; j < K_; ++j) {
                    const float p = Pn[k * K_ + j];                          // uniform
                    s0 = fmaf(p, vx[j], s0);
                    s1 = fmaf(p, vy[j], s1);
                }
                half2v r = {(_Float16)elu_f(s0), (_Float16)elu_f(s1)};
                *(half2v*)&fg[k * C_] = r;                                   // ds_write_b32
            }
        }
    }
    __syncthreads();

    // ---------------- phase 2: MFMA GEMMs ----------------
    // 16 waves = (g 0..1) x (ot 0..7): wave does node n0+g, output cols [ot*16, ot*16+16)
    const int w    = tid >> 6;
    const int lane = tid & 63;
    const int col  = lane & 15;      // a-frag row m / b-frag col o / C-frag col
    const int quad = lane >> 4;      // 0..3
    const int g    = w & 1;
    const int ot   = w >> 1;         // 0..7
    const int o0   = ot * 16;
    const int n    = n0 + g;

    floatx4 accC = (floatx4){0.f, 0.f, 0.f, 0.f};
    floatx4 accS = (floatx4){0.f, 0.f, 0.f, 0.f};

    // skip GEMM (no LDS dependency): x-row (M=16 x 128) @ Ws^T
    for (int k0 = 0; k0 < C_; k0 += 32) {
        half8 a;
        if (XF16) {
            a = *(const half8*)(x16 + ((size_t)col * N_ + n) * C_ + k0 + quad * 8);
        } else {
            const float* p = x + ((size_t)col * N_ + n) * C_ + k0 + quad * 8;
            const float4 x0 = *(const float4*)p;
            const float4 x1 = *(const float4*)(p + 4);
            a = (half8){(_Float16)x0.x, (_Float16)x0.y, (_Float16)x0.z, (_Float16)x0.w,
                        (_Float16)x1.x, (_Float16)x1.y, (_Float16)x1.z, (_Float16)x1.w};
        }
        half8 b;
        if (WF16) {
            b = ((const half8*)WsP)[(ot * 4 + (k0 >> 5)) * 64 + lane];
        } else {
            const float* q = (const float*)WsP + (size_t)(o0 + col) * C_ + k0 + quad * 8;
            const float4 w0 = *(const float4*)q;
            const float4 w1 = *(const float4*)(q + 4);
            b = (half8){(_Float16)w0.x, (_Float16)w0.y, (_Float16)w0.z, (_Float16)w0.w,
                        (_Float16)w1.x, (_Float16)w1.y, (_Float16)w1.z, (_Float16)w1.w};
        }
        accS = __builtin_amdgcn_mfma_f32_16x16x32_f16(a, b, accS, 0, 0, 0);
    }

    // conv GEMM: flat (M=16 x 1152) @ Wc^T -> 16x16 tile
    const _Float16* fg = &flat_s[g * (B_ * FPAD) + col * FPAD];
    for (int k0 = 0; k0 < FCONV; k0 += 32) {
        half8 a = *(const half8*)&fg[k0 + quad * 8];
        half8 b;
        if (WF16) {
            b = ((const half8*)WcP)[(ot * 36 + (k0 >> 5)) * 64 + lane];
        } else {
            const float* q = (const float*)WcP + (size_t)(o0 + col) * FCONV + k0 + quad * 8;
            const float4 w0 = *(const float4*)q;
            const float4 w1 = *(const float4*)(q + 4);
            b = (half8){(_Float16)w0.x, (_Float16)w0.y, (_Float16)w0.z, (_Float16)w0.w,
                        (_Float16)w1.x, (_Float16)w1.y, (_Float16)w1.z, (_Float16)w1.w};
        }
        accC = __builtin_amdgcn_mfma_f32_16x16x32_f16(a, b, accC, 0, 0, 0);
    }

    // ---------------- epilogue: out = elu(conv + bc) + skip + bs ----------------
    const float bcv = bc[o0 + col];
    const float bsv = bs[o0 + col];
    #pragma unroll
    for (int r = 0; r < 4; ++r) {
        const int m = quad * 4 + r;     // C/D: row = (lane>>4)*4 + reg
        const float z = elu_f(accC[r] + bcv);
        __builtin_nontemporal_store(z + accS[r] + bsv,
                                    &out[((size_t)m * N_ + n) * C_ + o0 + col]);
    }
}

extern "C" void kernel_launch(void* const* d_in, const int* in_sizes, int n_in,
                              void* d_out, int out_size, void* d_ws, size_t ws_size,
                              hipStream_t stream) {
    const float* x   = (const float*)d_in[0];
    const int*   idx = (const int*)  d_in[1];
    const float* P   = (const float*)d_in[2];
    const float* Wc  = (const float*)d_in[3];
    const float* bc  = (const float*)d_in[4];
    const float* Ws  = (const float*)d_in[5];
    const float* bs  = (const float*)d_in[6];
    float* out = (float*)d_out;

    const size_t x16_halfs = (size_t)B_ * N_ * C_;     // 33,554,432
    const size_t wc_halfs  = (size_t)8 * 36 * 64 * 8;  // 147,456
    const size_t wsk_halfs = (size_t)8 * 4 * 64 * 8;   // 16,384
    const size_t need_full = (x16_halfs + wc_halfs + wsk_halfs) * sizeof(_Float16);
    const size_t need_w    = (wc_halfs + wsk_halfs) * sizeof(_Float16);

    if (ws_size >= need_full) {
        _Float16* x16 = (_Float16*)d_ws;
        _Float16* WcF = x16 + x16_halfs;
        _Float16* WsF = WcF + wc_halfs;
        // 4,194,304 x-groups + 163,840 weight elems = 4,358,144 threads = 4256 blocks
        prep<<<dim3(4256), dim3(1024), 0, stream>>>(x, Wc, Ws, x16, WcF, WsF);
        hipFuncSetAttribute((const void*)paiconv_mfma<true, true>,
                            hipFuncAttributeMaxDynamicSharedMemorySize, LDS_BYTES);
        paiconv_mfma<true, true><<<dim3(N_ / G_), dim3(1024), LDS_BYTES, stream>>>(
            x, x16, idx, P, WcF, bc, WsF, bs, out);
    } else if (ws_size >= need_w) {
        _Float16* WcF = (_Float16*)d_ws;
        _Float16* WsF = WcF + wc_halfs;
        build_wfrag<<<dim3(576), dim3(256), 0, stream>>>(Wc, Ws, WcF, WsF);
        hipFuncSetAttribute((const void*)paiconv_mfma<false, true>,
                            hipFuncAttributeMaxDynamicSharedMemorySize, LDS_BYTES);
        paiconv_mfma<false, true><<<dim3(N_ / G_), dim3(1024), LDS_BYTES, stream>>>(
            x, nullptr, idx, P, WcF, bc, WsF, bs, out);
    } else {
        hipFuncSetAttribute((const void*)paiconv_mfma<false, false>,
                            hipFuncAttributeMaxDynamicSharedMemorySize, LDS_BYTES);
        paiconv_mfma<false, false><<<dim3(N_ / G_), dim3(1024), LDS_BYTES, stream>>>(
            x, nullptr, idx, P, Wc, bc, Ws, bs, out);
    }
}

// Round 4
// 501.941 us; speedup vs baseline: 1.2065x; 1.2065x over previous
//
#include <hip/hip_runtime.h>
#include <hip/hip_fp16.h>
#include <math.h>

// B=16, N=16384, C_IN=C_OUT=128, K=9
#define B_ 16
#define N_ 16384
#define C_ 128
#define K_ 9
#define FCONV 1152           // K_*C_
#define G_ 2                 // nodes per block
#define FPAD 1160            // flat row stride in halfs: 16B-aligned; 145 granules/row
#define LDS_BYTES (G_ * B_ * FPAD * 2)   // 74240 B dynamic LDS -> 2 blocks/CU

typedef _Float16 half8 __attribute__((ext_vector_type(8)));
typedef _Float16 half2v __attribute__((ext_vector_type(2)));
typedef float floatx4 __attribute__((ext_vector_type(4)));

__device__ __forceinline__ float elu_f(float v) {
    return v > 0.f ? v : (__expf(v) - 1.f);
}

// ---------------- prep: x -> f16 (nt-load x), W -> MFMA b-fragment-major f16 ----------------
//  conv frag: ((ot*36 + kc)*64 + lane)*8 + j = Wc[ot*16 + (lane&15)][kc*32 + (lane>>4)*8 + j]
//  skip frag: ((ot*4  + kc)*64 + lane)*8 + j = Ws[ot*16 + (lane&15)][kc*32 + (lane>>4)*8 + j]
__global__ __launch_bounds__(1024) void prep(
    const float* __restrict__ x, const float* __restrict__ Wc, const float* __restrict__ Ws,
    _Float16* __restrict__ x16, _Float16* __restrict__ WcF, _Float16* __restrict__ WsF)
{
    const int t = blockIdx.x * 1024 + threadIdx.x;
    const int NX8 = B_ * N_ * C_ / 8;   // 4,194,304 half8 groups
    if (t < NX8) {
        const floatx4* px = (const floatx4*)x + (size_t)t * 2;   // ext-vector: nt-load OK
        const floatx4 a = __builtin_nontemporal_load(px);        // stream: keep LLC for x16
        const floatx4 b = __builtin_nontemporal_load(px + 1);
        half8 h = {(_Float16)a.x, (_Float16)a.y, (_Float16)a.z, (_Float16)a.w,
                   (_Float16)b.x, (_Float16)b.y, (_Float16)b.z, (_Float16)b.w};
        *(half8*)(x16 + (size_t)t * 8) = h;
    } else {
        const int i = t - NX8;
        if (i < 8 * 36 * 64 * 8) {
            const int j = i & 7, lane = (i >> 3) & 63;
            const int rest = i >> 9;               // ot*36 + kc
            const int kc = rest % 36, ot = rest / 36;
            WcF[i] = (_Float16)Wc[(size_t)(ot * 16 + (lane & 15)) * FCONV + kc * 32 + (lane >> 4) * 8 + j];
        } else {
            const int i2 = i - 8 * 36 * 64 * 8;
            if (i2 < 8 * 4 * 64 * 8) {
                const int j = i2 & 7, lane = (i2 >> 3) & 63;
                const int rest = i2 >> 9;          // ot*4 + kc
                const int kc = rest & 3, ot = rest >> 2;
                WsF[i2] = (_Float16)Ws[(size_t)(ot * 16 + (lane & 15)) * C_ + kc * 32 + (lane >> 4) * 8 + j];
            }
        }
    }
}

// ---------------- main kernel: 512 threads, 8 waves; wave = output tile ot for BOTH nodes ----------------
__global__ __launch_bounds__(512, 4) void paiconv_mfma512(
    const _Float16* __restrict__ x16,    // (B,N,C) f16
    const int*      __restrict__ idx,    // (N,K)
    const float*    __restrict__ P,      // (N,K,K)
    const _Float16* __restrict__ WcF,    // fragment-major f16
    const float*    __restrict__ bc,
    const _Float16* __restrict__ WsF,
    const float*    __restrict__ bs,
    float*          __restrict__ out)    // (B,N,C_OUT)
{
    extern __shared__ _Float16 flat_s[];     // [G][16][FPAD] f16

    const int tid = threadIdx.x;
    const int n0  = blockIdx.x * G_;

    // ---------------- phase 1: gather + P-mix + ELU -> flat_s (f16) ----------------
    // thread = (mw = tid>>6 in 0..7, cp = tid&63). Handles batches {mw, mw+8}, channels {2cp,2cp+1},
    // both nodes. All 36 gather loads issued before any consumption (deep MLP).
    {
        const int cp = tid & 63;
        const int mw = tid >> 6;

        int id0[K_], id1[K_];
        #pragma unroll
        for (int j = 0; j < K_; ++j) id0[j] = idx[(size_t)n0 * K_ + j];          // uniform -> s_load
        #pragma unroll
        for (int j = 0; j < K_; ++j) id1[j] = idx[(size_t)(n0 + 1) * K_ + j];

        half2v vp[2][2][K_];     // [g][mi][j], packed channel pair
        #pragma unroll
        for (int mi = 0; mi < 2; ++mi) {
            const _Float16* xb = x16 + (size_t)(mw + mi * 8) * (N_ * C_) + 2 * cp;
            #pragma unroll
            for (int j = 0; j < K_; ++j)
                vp[0][mi][j] = *(const half2v*)(xb + (size_t)id0[j] * C_);
            #pragma unroll
            for (int j = 0; j < K_; ++j)
                vp[1][mi][j] = *(const half2v*)(xb + (size_t)id1[j] * C_);
        }

        #pragma unroll
        for (int g = 0; g < G_; ++g) {
            const float* Pn = P + (size_t)(n0 + g) * 81;
            #pragma unroll
            for (int mi = 0; mi < 2; ++mi) {
                const int m = mw + mi * 8;
                float vx[K_], vy[K_];
                #pragma unroll
                for (int j = 0; j < K_; ++j) {
                    vx[j] = (float)vp[g][mi][j][0];
                    vy[j] = (float)vp[g][mi][j][1];
                }
                _Float16* fg = &flat_s[g * (B_ * FPAD) + m * FPAD + 2 * cp];
                #pragma unroll
                for (int k = 0; k < K_; ++k) {
                    float s0 = 0.f, s1 = 0.f;
                    #pragma unroll
                    for (int j = 0; j < K_; ++j) {
                        const float p = Pn[k * K_ + j];                           // uniform
                        s0 = fmaf(p, vx[j], s0);
                        s1 = fmaf(p, vy[j], s1);
                    }
                    half2v r = {(_Float16)elu_f(s0), (_Float16)elu_f(s1)};
                    *(half2v*)&fg[k * C_] = r;                                    // ds_write_b32
                }
            }
        }
    }

    // ---------------- phase 2 setup: wave = ot (0..7), both nodes ----------------
    const int w    = tid >> 6;
    const int lane = tid & 63;
    const int col  = lane & 15;
    const int quad = lane >> 4;
    const int o0   = w * 16;

    const half8* WcF8 = (const half8*)WcF + (size_t)w * 36 * 64 + lane;   // stride 64 frags per k-step
    const half8* WsF8 = (const half8*)WsF + (size_t)w * 4 * 64 + lane;

    // pre-barrier issue: skip operands + first 8 conv b-frags.
    // These don't touch LDS; their latency hides under phase-1 math + barrier wait.
    half8 sb[4], sa0[4], sa1[4], bq[8];
    #pragma unroll
    for (int k4 = 0; k4 < 4; ++k4) {
        sb[k4]  = WsF8[k4 * 64];
        sa0[k4] = *(const half8*)(x16 + ((size_t)col * N_ + n0) * C_ + k4 * 32 + quad * 8);
        sa1[k4] = *(const half8*)(x16 + ((size_t)col * N_ + n0 + 1) * C_ + k4 * 32 + quad * 8);
    }
    #pragma unroll
    for (int p = 0; p < 8; ++p) bq[p] = WcF8[p * 64];

    __syncthreads();

    // skip GEMM: 2 independent acc chains, operands already resident
    floatx4 accS0 = (floatx4){0.f, 0.f, 0.f, 0.f};
    floatx4 accS1 = (floatx4){0.f, 0.f, 0.f, 0.f};
    #pragma unroll
    for (int k4 = 0; k4 < 4; ++k4) {
        accS0 = __builtin_amdgcn_mfma_f32_16x16x32_f16(sa0[k4], sb[k4], accS0, 0, 0, 0);
        accS1 = __builtin_amdgcn_mfma_f32_16x16x32_f16(sa1[k4], sb[k4], accS1, 0, 0, 0);
    }

    // conv GEMM: flat (16 x 1152) @ Wc^T, one b-frag feeds both nodes.
    // Software pipeline: b-frags 8-deep (LLC latency), a-frags 4-deep (LDS latency).
    const _Float16* fg0 = &flat_s[col * FPAD];
    const _Float16* fg1 = &flat_s[B_ * FPAD + col * FPAD];
    floatx4 accC0 = (floatx4){0.f, 0.f, 0.f, 0.f};
    floatx4 accC1 = (floatx4){0.f, 0.f, 0.f, 0.f};

    half8 a0q[4], a1q[4];
    #pragma unroll
    for (int p = 0; p < 4; ++p) {
        a0q[p] = *(const half8*)&fg0[p * 32 + quad * 8];
        a1q[p] = *(const half8*)&fg1[p * 32 + quad * 8];
    }
    #pragma unroll
    for (int k = 0; k < 36; ++k) {          // fully unrolled: ring indices are static (rule #20)
        const half8 b  = bq[k & 7];
        const half8 a0 = a0q[k & 3];
        const half8 a1 = a1q[k & 3];
        if (k + 8 < 36) bq[k & 7] = WcF8[(k + 8) * 64];
        if (k + 4 < 36) {
            a0q[k & 3] = *(const half8*)&fg0[(k + 4) * 32 + quad * 8];
            a1q[k & 3] = *(const half8*)&fg1[(k + 4) * 32 + quad * 8];
        }
        accC0 = __builtin_amdgcn_mfma_f32_16x16x32_f16(a0, b, accC0, 0, 0, 0);
        accC1 = __builtin_amdgcn_mfma_f32_16x16x32_f16(a1, b, accC1, 0, 0, 0);
    }

    // ---------------- epilogue: out = elu(conv + bc) + skip + bs ----------------
    const float bcv = bc[o0 + col];
    const float bsv = bs[o0 + col];
    #pragma unroll
    for (int r = 0; r < 4; ++r) {
        const int m = quad * 4 + r;         // C/D: row = (lane>>4)*4 + reg
        const float z0 = elu_f(accC0[r] + bcv) + accS0[r] + bsv;
        const float z1 = elu_f(accC1[r] + bcv) + accS1[r] + bsv;
        __builtin_nontemporal_store(z0, &out[((size_t)m * N_ + n0) * C_ + o0 + col]);
        __builtin_nontemporal_store(z1, &out[((size_t)m * N_ + n0 + 1) * C_ + o0 + col]);
    }
}

// ---------------- fallback (small workspace): round-2 structure ----------------
__global__ void build_wfrag(const float* __restrict__ Wc, const float* __restrict__ Ws,
                            _Float16* __restrict__ WcF, _Float16* __restrict__ WsF) {
    const int i = blockIdx.x * 256 + threadIdx.x;
    if (i < 8 * 36 * 64 * 8) {
        const int j = i & 7, lane = (i >> 3) & 63;
        const int rest = i >> 9;
        const int kc = rest % 36, ot = rest / 36;
        WcF[i] = (_Float16)Wc[(size_t)(ot * 16 + (lane & 15)) * FCONV + kc * 32 + (lane >> 4) * 8 + j];
    }
    if (i < 8 * 4 * 64 * 8) {
        const int j = i & 7, lane = (i >> 3) & 63;
        const int rest = i >> 9;
        const int kc = rest & 3, ot = rest >> 2;
        WsF[i] = (_Float16)Ws[(size_t)(ot * 16 + (lane & 15)) * C_ + kc * 32 + (lane >> 4) * 8 + j];
    }
}

template <bool WF16>
__global__ __launch_bounds__(1024, 8) void paiconv_legacy(
    const float* __restrict__ x, const int* __restrict__ idx, const float* __restrict__ P,
    const void* __restrict__ WcP, const float* __restrict__ bc,
    const void* __restrict__ WsP, const float* __restrict__ bs, float* __restrict__ out)
{
    extern __shared__ _Float16 flat_s[];
    const int tid = threadIdx.x;
    const int n0  = blockIdx.x * G_;
    {
        const int cp = tid & 63;
        const int m  = tid >> 6;
        #pragma unroll
        for (int g = 0; g < G_; ++g) {
            const int n = n0 + g;
            int id[K_];
            #pragma unroll
            for (int j = 0; j < K_; ++j) id[j] = idx[(size_t)n * K_ + j];
            float vx[K_], vy[K_];
            #pragma unroll
            for (int j = 0; j < K_; ++j) {
                const bool ok = (unsigned)id[j] < (unsigned)N_;
                const float* q = x + ((size_t)m * N_ + id[j]) * C_ + 2 * cp;
                float2 h = ok ? *(const float2*)q : (float2){0.f, 0.f};
                vx[j] = h.x; vy[j] = h.y;
            }
            const float* Pn = P + (size_t)n * 81;
            _Float16* fg = &flat_s[g * (B_ * FPAD) + m * FPAD + 2 * cp];
            #pragma unroll
            for (int k = 0; k < K_; ++k) {
                float s0 = 0.f, s1 = 0.f;
                #pragma unroll
                for (int j = 0; j < K_; ++j) {
                    const float p = Pn[k * K_ + j];
                    s0 = fmaf(p, vx[j], s0);
                    s1 = fmaf(p, vy[j], s1);
                }
                half2v r = {(_Float16)elu_f(s0), (_Float16)elu_f(s1)};
                *(half2v*)&fg[k * C_] = r;
            }
        }
    }
    __syncthreads();

    const int w = tid >> 6, lane = tid & 63;
    const int col = lane & 15, quad = lane >> 4;
    const int g = w & 1, ot = w >> 1, o0 = ot * 16;
    const int n = n0 + g;

    floatx4 accC = (floatx4){0.f, 0.f, 0.f, 0.f};
    floatx4 accS = (floatx4){0.f, 0.f, 0.f, 0.f};

    for (int k0 = 0; k0 < C_; k0 += 32) {
        const float* p = x + ((size_t)col * N_ + n) * C_ + k0 + quad * 8;
        const float4 x0 = *(const float4*)p;
        const float4 x1 = *(const float4*)(p + 4);
        half8 a = (half8){(_Float16)x0.x, (_Float16)x0.y, (_Float16)x0.z, (_Float16)x0.w,
                          (_Float16)x1.x, (_Float16)x1.y, (_Float16)x1.z, (_Float16)x1.w};
        half8 b;
        if (WF16) {
            b = ((const half8*)WsP)[(ot * 4 + (k0 >> 5)) * 64 + lane];
        } else {
            const float* q = (const float*)WsP + (size_t)(o0 + col) * C_ + k0 + quad * 8;
            const float4 w0 = *(const float4*)q;
            const float4 w1 = *(const float4*)(q + 4);
            b = (half8){(_Float16)w0.x, (_Float16)w0.y, (_Float16)w0.z, (_Float16)w0.w,
                        (_Float16)w1.x, (_Float16)w1.y, (_Float16)w1.z, (_Float16)w1.w};
        }
        accS = __builtin_amdgcn_mfma_f32_16x16x32_f16(a, b, accS, 0, 0, 0);
    }
    const _Float16* fg = &flat_s[g * (B_ * FPAD) + col * FPAD];
    for (int k0 = 0; k0 < FCONV; k0 += 32) {
        half8 a = *(const half8*)&fg[k0 + quad * 8];
        half8 b;
        if (WF16) {
            b = ((const half8*)WcP)[(ot * 36 + (k0 >> 5)) * 64 + lane];
        } else {
            const float* q = (const float*)WcP + (size_t)(o0 + col) * FCONV + k0 + quad * 8;
            const float4 w0 = *(const float4*)q;
            const float4 w1 = *(const float4*)(q + 4);
            b = (half8){(_Float16)w0.x, (_Float16)w0.y, (_Float16)w0.z, (_Float16)w0.w,
                        (_Float16)w1.x, (_Float16)w1.y, (_Float16)w1.z, (_Float16)w1.w};
        }
        accC = __builtin_amdgcn_mfma_f32_16x16x32_f16(a, b, accC, 0, 0, 0);
    }
    const float bcv = bc[o0 + col];
    const float bsv = bs[o0 + col];
    #pragma unroll
    for (int r = 0; r < 4; ++r) {
        const int m = quad * 4 + r;
        const float z = elu_f(accC[r] + bcv);
        __builtin_nontemporal_store(z + accS[r] + bsv, &out[((size_t)m * N_ + n) * C_ + o0 + col]);
    }
}

extern "C" void kernel_launch(void* const* d_in, const int* in_sizes, int n_in,
                              void* d_out, int out_size, void* d_ws, size_t ws_size,
                              hipStream_t stream) {
    const float* x   = (const float*)d_in[0];
    const int*   idx = (const int*)  d_in[1];
    const float* P   = (const float*)d_in[2];
    const float* Wc  = (const float*)d_in[3];
    const float* bc  = (const float*)d_in[4];
    const float* Ws  = (const float*)d_in[5];
    const float* bs  = (const float*)d_in[6];
    float* out = (float*)d_out;

    const size_t x16_halfs = (size_t)B_ * N_ * C_;     // 33,554,432
    const size_t wc_halfs  = (size_t)8 * 36 * 64 * 8;  // 147,456
    const size_t wsk_halfs = (size_t)8 * 4 * 64 * 8;   // 16,384
    const size_t need_full = (x16_halfs + wc_halfs + wsk_halfs) * sizeof(_Float16);
    const size_t need_w    = (wc_halfs + wsk_halfs) * sizeof(_Float16);

    if (ws_size >= need_full) {
        _Float16* x16 = (_Float16*)d_ws;
        _Float16* WcF = x16 + x16_halfs;
        _Float16* WsF = WcF + wc_halfs;
        prep<<<dim3(4256), dim3(1024), 0, stream>>>(x, Wc, Ws, x16, WcF, WsF);
        hipFuncSetAttribute((const void*)paiconv_mfma512,
                            hipFuncAttributeMaxDynamicSharedMemorySize, LDS_BYTES);
        paiconv_mfma512<<<dim3(N_ / G_), dim3(512), LDS_BYTES, stream>>>(
            x16, idx, P, WcF, bc, WsF, bs, out);
    } else if (ws_size >= need_w) {
        _Float16* WcF = (_Float16*)d_ws;
        _Float16* WsF = WcF + wc_halfs;
        build_wfrag<<<dim3(576), dim3(256), 0, stream>>>(Wc, Ws, WcF, WsF);
        hipFuncSetAttribute((const void*)paiconv_legacy<true>,
                            hipFuncAttributeMaxDynamicSharedMemorySize, LDS_BYTES);
        paiconv_legacy<true><<<dim3(N_ / G_), dim3(1024), LDS_BYTES, stream>>>(
            x, idx, P, WcF, bc, WsF, bs, out);
    } else {
        hipFuncSetAttribute((const void*)paiconv_legacy<false>,
                            hipFuncAttributeMaxDynamicSharedMemorySize, LDS_BYTES);
        paiconv_legacy<false><<<dim3(N_ / G_), dim3(1024), LDS_BYTES, stream>>>(
            x, idx, P, Wc, bc, Ws, bs, out);
    }
}